// Round 7
// baseline (36.717 us; speedup 1.0000x reference)
//
#include <hip/hip_runtime.h>

// GrowingSignature: truncated iterated-sums signature, levels 1..4, F=4.
// x: (32, 512, 4) f32;  out: (32, 512, 341) f32.
// 64-thread blocks, 4 words/lane: lane = (a,b,c), e=0..3 vectorized.
// CS=8, C=64: sigA writes 64 chunk sigs/batch; sigC Chen-combines its
// prefix straight from global (L2-resident) and scans 8 output rows.
// Word layout: len1 cols 1..4, len2 5..20, len3 21..84, len4 85..340;
// word (a,b,c,e) -> col 85+64a+16b+4c+e = 85+4*lane+e.

#define SIG_B 32
#define SIG_L 512
#define SIG_NSTEP 511
#define SIG_ROW 341
#define SIG_CS 8             // chunk size (increments)
#define SIG_C 64             // chunks per batch
#define SIG_PAD 344          // workspace row stride (floats)

// 4-wide float vector with 4-byte alignment (cols 85+4*lane are not 16B-aligned;
// compiler emits dwordx4 if legal, else splits — correct either way).
typedef float vf4 __attribute__((ext_vector_type(4), aligned(4)));

__device__ __forceinline__ void stage_d(const float* __restrict__ xb,
                                        float4* dlds, int tid, int nt) {
    if (tid < SIG_CS) {
        float4 d = make_float4(0.f, 0.f, 0.f, 0.f);
        if (tid < nt) {
            float4 x0 = *(const float4*)(xb + tid * 4);
            float4 x1 = *(const float4*)(xb + tid * 4 + 4);
            d = make_float4(x1.x - x0.x, x1.y - x0.y, x1.z - x0.z, x1.w - x0.w);
        }
        dlds[tid] = d;   // zero-padded tail
    }
}

// ---------- Kernel A: chunk-local signatures (one wave per chunk) ----------
__global__ __launch_bounds__(64) void sigA(const float* __restrict__ x,
                                           float* __restrict__ Lsig) {
    const int bc = blockIdx.x;
    const int b = bc >> 6, c = bc & 63;
    const int tid = threadIdx.x;
    const int t0 = c * SIG_CS;
    const int nt = min(SIG_CS, SIG_NSTEP - t0);   // 8, or 7 for c=63

    __shared__ float4 dlds[SIG_CS];
    stage_d(x + ((size_t)b * SIG_L + t0) * 4, dlds, tid, nt);
    __syncthreads();

    const int a = tid >> 4, b2 = (tid >> 2) & 3, cc = tid & 3;
    const float* dl = (const float*)dlds;

    float s1 = 0.f, s2 = 0.f, s3 = 0.f;
    vf4 s4v = {0.f, 0.f, 0.f, 0.f};
#pragma unroll
    for (int t = 0; t < SIG_CS; ++t) {
        const float da = dl[4 * t + a], db = dl[4 * t + b2], dc = dl[4 * t + cc];
        const float4 d4 = dlds[t];                 // broadcast b128
        const vf4 dv = {d4.x, d4.y, d4.z, d4.w};
        s4v += s3 * dv;    // top level first: consumes pre-update s3
        s3 += s2 * dc;
        s2 += s1 * db;
        s1 += da;
    }
    float* Lr = Lsig + (size_t)bc * SIG_PAD;
    if ((tid & 15) == 0) Lr[1 + a] = s1;           // level 1 (4 words)
    if (cc == 0)         Lr[5 + (tid >> 2)] = s2;  // level 2 (16 words)
    Lr[21 + tid] = s3;                             // level 3 (64 words)
    *(vf4*)(Lr + 85 + 4 * tid) = s4v;              // level 4 (256 words)
}

// ---------- Kernel C: prefix combine (from global) + output scan ----------
__global__ __launch_bounds__(64) void sigC(const float* __restrict__ x,
                                           const float* __restrict__ Lsig,
                                           float* __restrict__ out) {
    const int bc = blockIdx.x;
    const int b = bc >> 6, c = bc & 63;
    const int tid = threadIdx.x;
    const int t0 = c * SIG_CS;
    const int nt = min(SIG_CS, SIG_NSTEP - t0);

    __shared__ float4 dlds[SIG_CS];
    stage_d(x + ((size_t)b * SIG_L + t0) * 4, dlds, tid, nt);
    __syncthreads();

    const int a = tid >> 4, b2 = (tid >> 2) & 3, cc = tid & 3;
    const float* dl = (const float*)dlds;

    // Chen-combine chunk sigs 0..c-1 (L2-resident reads, compiler-pipelined).
    float q1 = 0.f, q2 = 0.f, q3 = 0.f;
    vf4 q4 = {0.f, 0.f, 0.f, 0.f};
    const float* Lb = Lsig + (size_t)(b * SIG_C) * SIG_PAD;
    for (int j = 0; j < c; ++j) {
        const float* Lr = Lb + (size_t)j * SIG_PAD;
        const float l1a = Lr[1 + a], l1b = Lr[1 + b2], l1c = Lr[1 + cc];
        const vf4 l1v   = *(const vf4*)(Lr + 1);
        const float l2ab = Lr[5 + 4 * a + b2], l2bc = Lr[5 + 4 * b2 + cc];
        const vf4 l2cv  = *(const vf4*)(Lr + 5 + 4 * cc);
        const float l3abc = Lr[21 + 16 * a + 4 * b2 + cc];
        const vf4 l3bcv = *(const vf4*)(Lr + 21 + 16 * b2 + 4 * cc);
        const vf4 l4v   = *(const vf4*)(Lr + 85 + 4 * tid);
        q4 += q3 * l1v + q2 * l2cv + q1 * l3bcv + l4v;  // pre-update q1..q3
        q3 += q2 * l1c + q1 * l2bc + l3abc;
        q2 += q1 * l1b + l2ab;
        q1 += l1a;
    }

    if (c == 0) {  // row 0: [1, zeros]
        float* r0 = out + (size_t)b * SIG_L * SIG_ROW;
        for (int i = tid; i < SIG_ROW; i += 64)
            __builtin_nontemporal_store(i == 0 ? 1.0f : 0.0f, r0 + i);
    }

    // Local suffix chains (4 words/lane; e-dim vectorized).
    float s1 = 0.f, s2 = 0.f, s3 = 0.f;
    float x1 = 0.f, x2 = 0.f, v1 = 0.f;
    vf4 s4v = {0.f, 0.f, 0.f, 0.f}, x3v = {0.f, 0.f, 0.f, 0.f};
    vf4 v2v = {0.f, 0.f, 0.f, 0.f}, u1v = {0.f, 0.f, 0.f, 0.f};

    float* row = out + ((size_t)b * SIG_L + t0 + 1) * SIG_ROW;
#pragma unroll
    for (int t = 0; t < SIG_CS; ++t) {
        const float da = dl[4 * t + a], db = dl[4 * t + b2], dc = dl[4 * t + cc];
        const float4 d4 = dlds[t];
        const vf4 dv = {d4.x, d4.y, d4.z, d4.w};
        // top level first: each update consumes pre-update lower chain
        s4v += s3 * dv;  s3 += s2 * dc;  s2 += s1 * db;  s1 += da;
        x3v += x2 * dv;  x2 += x1 * dc;  x1 += db;
        v2v += v1 * dv;  v1 += dc;
        u1v += dv;

        if (t < nt) {   // uniform guard (only c=63 pads one step)
            float* r = row + (size_t)t * SIG_ROW;
            vf4 r4 = q4 + s4v + q3 * u1v + q2 * v2v + q1 * x3v;
            const float r3 = q3 + s3 + q2 * v1 + q1 * x2;
            __builtin_nontemporal_store(r4, (vf4*)(r + 85 + 4 * tid));
            __builtin_nontemporal_store(r3, r + 21 + tid);
            if (cc == 0)
                __builtin_nontemporal_store(q2 + s2 + q1 * x1, r + 5 + (tid >> 2));
            if ((tid & 15) == 0)
                __builtin_nontemporal_store(q1 + s1, r + 1 + a);
            if (tid == 0)
                __builtin_nontemporal_store(1.0f, r + 0);
        }
    }
}

extern "C" void kernel_launch(void* const* d_in, const int* in_sizes, int n_in,
                              void* d_out, int out_size, void* d_ws, size_t ws_size,
                              hipStream_t stream) {
    const float* x = (const float*)d_in[0];   // (32, 512, 4) f32
    float* out = (float*)d_out;               // (32, 512, 341) f32
    float* Lsig = (float*)d_ws;               // 2048 * 344 floats (~2.7 MB)

    sigA<<<SIG_B * SIG_C, 64, 0, stream>>>(x, Lsig);
    sigC<<<SIG_B * SIG_C, 64, 0, stream>>>(x, Lsig, out);
}

// Round 8
// 21.373 us; speedup vs baseline: 1.7179x; 1.7179x over previous
//
#include <hip/hip_runtime.h>

// GrowingSignature: truncated iterated-sums signature, levels 1..4, F=4.
// x: (32, 512, 4) f32;  out: (32, 512, 341) f32.
// 2-kernel chunked scan (CS=32, C=16). Key simplification: the output scan
// is the plain running-signature recursion seeded with the Chen-combined
// chunk prefix — a single-step Chen product only touches level 1, so the
// per-step update is 4 FMAs per lane (no suffix chains needed).
// Word layout (signatory order): len1 cols 1..4, len2 cols 5..20,
// len3 cols 21..84, len4 cols 85..340; word (a,b,c,e) -> 85+64a+16b+4c+e.

#define SIG_B 32
#define SIG_L 512
#define SIG_NSTEP 511
#define SIG_ROW 341
#define SIG_CS 32            // chunk size (increments)
#define SIG_C 16             // chunks per batch
#define SIG_PAD 344          // padded row stride in workspace (floats, %4==0)

// ---------- Kernel A: local chunk signatures ----------
__global__ __launch_bounds__(256) void sigA(const float* __restrict__ x,
                                            float* __restrict__ Lsig) {
    const int bc = blockIdx.x;
    const int b = bc / SIG_C, c = bc % SIG_C;
    const int tid = threadIdx.x;
    const int t0 = c * SIG_CS;
    const int nt = min(SIG_CS, SIG_NSTEP - t0);   // 32, or 31 for last chunk

    __shared__ float dlds[SIG_CS * 4];
    const float* xb = x + ((size_t)b * SIG_L + t0) * 4;
    if (tid < nt) {
        float4 x0 = *(const float4*)(xb + tid * 4);
        float4 x1 = *(const float4*)(xb + (tid + 1) * 4);
        *(float4*)(dlds + tid * 4) =
            make_float4(x1.x - x0.x, x1.y - x0.y, x1.z - x0.z, x1.w - x0.w);
    }
    __syncthreads();

    const int a = tid >> 6, bb = (tid >> 4) & 3, cc = (tid >> 2) & 3, ee = tid & 3;
    float s1 = 0.f, s2 = 0.f, s3 = 0.f, s4 = 0.f;
    const float* dp = dlds;
    for (int t = 0; t < nt; ++t) {
        const float da = dp[a], db = dp[bb], dc = dp[cc], de = dp[ee];
        dp += 4;
        s4 = fmaf(s3, de, s4);  // top level first: consumes pre-update s3
        s3 = fmaf(s2, dc, s3);
        s2 = fmaf(s1, db, s2);
        s1 += da;
    }
    float* Lr = Lsig + (size_t)bc * SIG_PAD;
    if ((tid & 63) == 0) Lr[1 + a] = s1;
    if ((tid & 15) == 0) Lr[5 + (tid >> 4)] = s2;
    if ((tid & 3) == 0)  Lr[21 + (tid >> 2)] = s3;
    Lr[85 + tid] = s4;
}

// ---------- Kernel C: prefix combine + plain running-signature scan ----------
__global__ __launch_bounds__(256) void sigC(const float* __restrict__ x,
                                            const float* __restrict__ Lsig,
                                            float* __restrict__ out) {
    const int bc = blockIdx.x;
    const int b = bc / SIG_C, c = bc % SIG_C;
    const int tid = threadIdx.x;
    const int t0 = c * SIG_CS;
    const int nt = min(SIG_CS, SIG_NSTEP - t0);

    __shared__ float dlds[SIG_CS * 4];
    __shared__ float L[SIG_C * SIG_PAD];

    const float* xb = x + ((size_t)b * SIG_L + t0) * 4;
    if (tid < nt) {
        float4 x0 = *(const float4*)(xb + tid * 4);
        float4 x1 = *(const float4*)(xb + (tid + 1) * 4);
        *(float4*)(dlds + tid * 4) =
            make_float4(x1.x - x0.x, x1.y - x0.y, x1.z - x0.z, x1.w - x0.w);
    }
    // Stage the c preceding chunk signatures (only what this block combines).
    {
        const float4* Lb4 = (const float4*)(Lsig + (size_t)b * SIG_C * SIG_PAD);
        float4* L4p = (float4*)L;
        const int n4 = c * (SIG_PAD / 4);
        for (int i = tid; i < n4; i += 256) L4p[i] = Lb4[i];
    }
    __syncthreads();

    const int a = tid >> 6, bb = (tid >> 4) & 3, cc = (tid >> 2) & 3, ee = tid & 3;

    // Chen-combine chunks 0..c-1 -> prefix (p1..p4) for this lane's word.
    float p1 = 0.f, p2 = 0.f, p3 = 0.f, p4 = 0.f;
    for (int j = 0; j < c; ++j) {
        const float* Lc = L + j * SIG_PAD;
        const float l1a = Lc[1 + a], l1b = Lc[1 + bb], l1c = Lc[1 + cc], l1e = Lc[1 + ee];
        const float l2ab = Lc[5 + 4 * a + bb], l2bc = Lc[5 + 4 * bb + cc],
                    l2ce = Lc[5 + 4 * cc + ee];
        const float l3abc = Lc[21 + 16 * a + 4 * bb + cc],
                    l3bce = Lc[21 + 16 * bb + 4 * cc + ee];
        const float l4 = Lc[85 + tid];
        p4 += p3 * l1e + p2 * l2ce + p1 * l3bce + l4;  // uses pre-update p1..p3
        p3 += p2 * l1c + p1 * l2bc + l3abc;
        p2 += p1 * l1b + l2ab;
        p1 += l1a;
    }

    float* row = out + ((size_t)b * SIG_L + (t0 + 1)) * SIG_ROW;

    if (c == 0) {  // row 0: [1, zeros]
        float* r0 = out + (size_t)b * SIG_L * SIG_ROW;
        if (tid == 0)        __builtin_nontemporal_store(1.0f, r0 + 0);
        if ((tid & 63) == 0) __builtin_nontemporal_store(0.f, r0 + 1 + a);
        if ((tid & 15) == 0) __builtin_nontemporal_store(0.f, r0 + 5 + (tid >> 4));
        if ((tid & 3) == 0)  __builtin_nontemporal_store(0.f, r0 + 21 + (tid >> 2));
        __builtin_nontemporal_store(0.f, r0 + 85 + tid);
    }

    // Plain running-signature recursion seeded with the prefix: 4 FMA/step.
    const float* dp = dlds;
    for (int t = 0; t < nt; ++t) {
        const float da = dp[a], db = dp[bb], dc = dp[cc], de = dp[ee];
        dp += 4;
        p4 = fmaf(p3, de, p4);  // top level first: consumes pre-update p3
        p3 = fmaf(p2, dc, p3);
        p2 = fmaf(p1, db, p2);
        p1 += da;

        if (tid == 0)        __builtin_nontemporal_store(1.0f, row + 0);
        if ((tid & 63) == 0) __builtin_nontemporal_store(p1, row + 1 + a);
        if ((tid & 15) == 0) __builtin_nontemporal_store(p2, row + 5 + (tid >> 4));
        if ((tid & 3) == 0)  __builtin_nontemporal_store(p3, row + 21 + (tid >> 2));
        __builtin_nontemporal_store(p4, row + 85 + tid);  // coalesced
        row += SIG_ROW;
    }
}

extern "C" void kernel_launch(void* const* d_in, const int* in_sizes, int n_in,
                              void* d_out, int out_size, void* d_ws, size_t ws_size,
                              hipStream_t stream) {
    const float* x = (const float*)d_in[0];   // (32, 512, 4) f32
    float* out = (float*)d_out;               // (32, 512, 341) f32
    float* Lsig = (float*)d_ws;               // 512 * 344 floats

    sigA<<<SIG_B * SIG_C, 256, 0, stream>>>(x, Lsig);
    sigC<<<SIG_B * SIG_C, 256, 0, stream>>>(x, Lsig, out);
}